// Round 9
// baseline (65.845 us; speedup 1.0000x reference)
//
#include <hip/hip_runtime.h>
#include <hip/hip_bf16.h>

#define BB 4
#define SS 1024
#define NSD (BB*SS*64)

typedef __attribute__((ext_vector_type(4))) float f32x4;
typedef __attribute__((ext_vector_type(8))) short bf16x8;

__device__ __forceinline__ float fast_exp2(float x) { return __builtin_amdgcn_exp2f(x); }
__device__ __forceinline__ float fast_rcp(float x)  { return __builtin_amdgcn_rcpf(x); }

__device__ __forceinline__ unsigned short f2bf(float f) {
    unsigned int u = __builtin_bit_cast(unsigned int, f);
    u += 0x7fffu + ((u >> 16) & 1u);
    return (unsigned short)(u >> 16);
}
__device__ __forceinline__ float bf2f(unsigned short u) {
    unsigned int v = (unsigned int)u << 16;
    return __builtin_bit_cast(float, v);
}

// sum of 4 sigmoids 1/(1+eq_d*ek_d) with one reciprocal
__device__ __forceinline__ float sig4(const f32x4 eq, const f32x4 ek) {
    float A = __builtin_fmaf(eq[0], ek[0], 1.0f);
    float B = __builtin_fmaf(eq[1], ek[1], 1.0f);
    float C = __builtin_fmaf(eq[2], ek[2], 1.0f);
    float D = __builtin_fmaf(eq[3], ek[3], 1.0f);
    float AB = A*B, CD = C*D;
    float num = __builtin_fmaf(A+B, CD, (C+D)*AB);
    return num * fast_rcp(AB*CD);
}

// ---------------------------------------------------------------------------
// K1: projections + hi/lo bf16 splits + exf (row-major) + exfT4 (d-quad-packed
// transpose: [B][16][S][4], lane-coalescible f32x4 per k).
// ---------------------------------------------------------------------------
__global__ __launch_bounds__(256) void k_proj(
    const float* __restrict__ x, const float* __restrict__ Wq,
    const float* __restrict__ Wk, const float* __restrict__ bkv,
    const float* __restrict__ Wv,
    unsigned short* __restrict__ qh, unsigned short* __restrict__ ql,
    unsigned short* __restrict__ kh, unsigned short* __restrict__ kl,
    unsigned short* __restrict__ xh, unsigned short* __restrict__ xlo,
    float* __restrict__ exf, float* __restrict__ exfT4,
    unsigned short* __restrict__ xT, unsigned short* __restrict__ vT)
{
    __shared__ float xsh[4*68];
    const int t = threadIdx.x;
    const int r = t & 3, cc = t >> 2;
    const int row0 = blockIdx.x * 4;
    if (t < 64) {
        const int rr = t >> 4, seg = (t & 15) * 4;
        *(f32x4*)(xsh + rr*68 + seg) =
            *(const f32x4*)(x + (size_t)(row0 + rr)*64 + seg);
    }
    __syncthreads();

    const float* wqp = Wq + cc*64;
    const float* wkp = Wk + cc*64;
    const float* wvp = Wv + cc*64;
    float aq = 0.f, ak = 0.f, av = 0.f;
    #pragma unroll 4
    for (int e0 = 0; e0 < 64; e0 += 4) {
        f32x4 xv = *(const f32x4*)(xsh + r*68 + e0);
        f32x4 q4 = *(const f32x4*)(wqp + e0);
        f32x4 k4 = *(const f32x4*)(wkp + e0);
        f32x4 v4 = *(const f32x4*)(wvp + e0);
        #pragma unroll
        for (int u = 0; u < 4; ++u) {
            aq = __builtin_fmaf(xv[u], q4[u], aq);
            ak = __builtin_fmaf(xv[u], k4[u], ak);
            av = __builtin_fmaf(xv[u], v4[u], av);
        }
    }
    const int row = row0 + r;
    const int b = row >> 10, srow = row & 1023;
    const float C2 = 2.8853900817779268f;   // 2*log2(e)
    ak += bkv[cc];
    const size_t idx = (size_t)row*64 + cc;
    unsigned short h;
    h = f2bf(aq); qh[idx] = h; ql[idx] = f2bf(aq - bf2f(h));
    h = f2bf(ak); kh[idx] = h; kl[idx] = f2bf(ak - bf2f(h));
    const float xv_ = xsh[r*68 + cc];
    h = f2bf(xv_); xh[idx] = h; xlo[idx] = f2bf(xv_ - bf2f(h));
    const float e2x = fast_exp2(C2 * xv_);
    exf[idx] = e2x;
    exfT4[(((size_t)b*16 + (cc >> 2))*1024 + srow)*4 + (cc & 3)] = e2x;
    xT[((size_t)b*64 + cc)*1024 + srow] = h;
    vT[((size_t)b*64 + cc)*1024 + srow] = f2bf(av);
}

// ---------------------------------------------------------------------------
// K2a: branch 3. 512 blocks x 256. Block -> (b, qt[16q], half); wave s8 =
// half*4+wv handles k-chunks c = s8, s8+8, ... (64k each).
// Lane = one k-row: exk (64 f32) in REGISTERS from exfT4 (coalesced).
// eq via LDS broadcast reads (same addr all lanes -> conflict-free).
// P per-wave LDS [16][72] (r2-verified A-frag layout), NO barriers in loop.
// lsum recomputed from af fragments (== what MFMA sums). Slots 4+s8.
// ---------------------------------------------------------------------------
__global__ __launch_bounds__(256) void k_br3(
    const float* __restrict__ exf, const float* __restrict__ exfT4,
    const unsigned short* __restrict__ xT,
    float* __restrict__ po, float* __restrict__ lb)
{
    __shared__ float eqb[16*64];
    __shared__ unsigned short Plb[4][16*72];
    const int t = threadIdx.x;
    const int lane = t & 63, wv = t >> 6;
    const int l15 = lane & 15, g = lane >> 4;
    const int bx = blockIdx.x;
    const int qt = 63 - (bx >> 3);        // heavy tiles dispatch first
    const int b = (bx >> 1) & 3;
    const int half = bx & 1;
    const int s8 = half*4 + wv;
    const int q0 = qt * 16;
    const int nch = (qt >> 2) + 1;        // 64k-chunks covering causal range

    {   // stage eq [16][64] (no pad needed: reads are broadcast)
        const int r0 = t >> 4, m0 = t & 15;
        *(f32x4*)(eqb + r0*64 + m0*4) =
            *(const f32x4*)(exf + ((size_t)b*SS + q0 + r0)*64 + m0*4);
    }
    __syncthreads();

    unsigned short* Plw = Plb[wv];
    const unsigned short* vb = xT + (size_t)b*64*1024;
    const float* ekbase = exfT4 + (size_t)b*16*4096;
    f32x4 acc[4];
    #pragma unroll
    for (int d = 0; d < 4; ++d) acc[d] = (f32x4){0.f,0.f,0.f,0.f};
    float lsum = 0.f;

    for (int c = s8; c < nch; c += 8) {
        const int kc = c * 64;
        const int k = kc + lane;
        // ek into registers: 16 coalesced b128 loads
        f32x4 ek[16];
        #pragma unroll
        for (int dq = 0; dq < 16; ++dq)
            ek[dq] = *(const f32x4*)(ekbase + ((size_t)dq*1024 + k)*4);
        // scores for 16 q's; 4 independent chains per q for ILP
        #pragma unroll 2
        for (int q = 0; q < 16; ++q) {
            float ar0 = 0.f, ar1 = 0.f, ar2 = 0.f, ar3 = 0.f;
            const float* eqr = eqb + q*64;
            #pragma unroll
            for (int dq = 0; dq < 16; dq += 4) {
                ar0 += sig4(*(const f32x4*)(eqr + dq*4),       ek[dq]);
                ar1 += sig4(*(const f32x4*)(eqr + dq*4 + 4),   ek[dq+1]);
                ar2 += sig4(*(const f32x4*)(eqr + dq*4 + 8),   ek[dq+2]);
                ar3 += sig4(*(const f32x4*)(eqr + dq*4 + 12),  ek[dq+3]);
            }
            const float ar = (ar0 + ar1) + (ar2 + ar3);
            // p = e^{s3-32}, s3 = 64 - 2*ar
            float e = (k <= q0 + q)
                ? fast_exp2(__builtin_fmaf(ar, -2.8853900817779268f,
                                           46.166241308446475f))
                : 0.f;
            Plw[q*72 + lane] = f2bf(e);
        }
        // PV + lsum from the same fragments (per-wave LDS: no barrier needed)
        float ls = 0.f;
        #pragma unroll
        for (int ks = 0; ks < 2; ++ks) {
            bf16x8 af = *(const bf16x8*)(Plw + l15*72 + ks*32 + g*8);
            #pragma unroll
            for (int j = 0; j < 8; ++j) ls += bf2f((unsigned short)af[j]);
            #pragma unroll
            for (int db = 0; db < 4; ++db) {
                bf16x8 bf_ = *(const bf16x8*)(vb + (size_t)(db*16 + l15)*1024 + kc + ks*32 + g*8);
                acc[db] = __builtin_amdgcn_mfma_f32_16x16x32_bf16(af, bf_, acc[db], 0, 0, 0);
            }
        }
        lsum += ls;
    }
    // af covers q=l15; reduce partial sums over the 4 lane-groups
    lsum += __shfl_xor(lsum, 16, 64);
    lsum += __shfl_xor(lsum, 32, 64);

    const size_t slot = 4 + s8;
    if (lane < 16)
        lb[slot*(size_t)(BB*SS) + (size_t)b*SS + q0 + lane] = lsum;
    float* pob = po + slot*(size_t)NSD + ((size_t)b*SS + q0)*64;
    #pragma unroll
    for (int i = 0; i < 4; ++i) {
        const int rr = g*4 + i;
        #pragma unroll
        for (int db = 0; db < 4; ++db)
            pob[(size_t)rr*64 + db*16 + l15] = acc[db][i];
    }
}

// ---------------------------------------------------------------------------
// K2b: branches 1,2 (split-bf16 MFMA scores) — round-7 path, own kernel so
// it keeps small LDS / high occupancy. 1024 blocks x 256. Slots 0..3.
// ---------------------------------------------------------------------------
__global__ __launch_bounds__(256) void k_br12(
    const unsigned short* __restrict__ xh, const unsigned short* __restrict__ xlo,
    const unsigned short* __restrict__ qh, const unsigned short* __restrict__ ql,
    const unsigned short* __restrict__ kh, const unsigned short* __restrict__ kl,
    const unsigned short* __restrict__ xT, const unsigned short* __restrict__ vT,
    const float* __restrict__ attn_scale,
    float* __restrict__ po, float* __restrict__ lb)
{
    __shared__ unsigned short Pl[16*72];
    __shared__ float lpart[4][16];
    const int t = threadIdx.x;
    const int lane = t & 63, wv = t >> 6;
    const int l15 = lane & 15, g = lane >> 4;
    const float LOG2E = 1.4426950408889634f;

    const int y = blockIdx.x;
    const int split = y & 1, b = (y >> 1) & 3;
    const int qt = 63 - ((y >> 3) & 63);
    const int br = (y >> 9) & 1;
    const int q0 = qt * 16;
    const int nc = (qt >> 2) + 1;

    const unsigned short* Ah_p = (br ? qh : xh) + ((size_t)b*SS + q0)*64;
    const unsigned short* Al_p = (br ? ql : xlo) + ((size_t)b*SS + q0)*64;
    const unsigned short* Bh_p = (br ? kh : xh) + (size_t)b*SS*64;
    const unsigned short* Bl_p = (br ? kl : xlo) + (size_t)b*SS*64;
    const unsigned short* Vb   = (br ? vT : xT) + (size_t)b*64*1024;

    const int ko = g * 8;
    bf16x8 Ah0 = *(const bf16x8*)(Ah_p + (size_t)l15*64 + ko);
    bf16x8 Ah1 = *(const bf16x8*)(Ah_p + (size_t)l15*64 + 32 + ko);
    bf16x8 Al0 = *(const bf16x8*)(Al_p + (size_t)l15*64 + ko);
    bf16x8 Al1 = *(const bf16x8*)(Al_p + (size_t)l15*64 + 32 + ko);

    const float pscale = br ? (0.125f * attn_scale[0] * LOG2E) : LOG2E;
    const float pshift = br ? 0.f : (-64.f * LOG2E);

    f32x4 lacc = {0,0,0,0};
    f32x4 oacc = {0,0,0,0};

    for (int c = split; c < nc; c += 2) {
        const int kc = c * 64;
        const int krow = kc + wv*16 + l15;
        bf16x8 Bh0 = *(const bf16x8*)(Bh_p + (size_t)krow*64 + ko);
        bf16x8 Bh1 = *(const bf16x8*)(Bh_p + (size_t)krow*64 + 32 + ko);
        bf16x8 Bl0 = *(const bf16x8*)(Bl_p + (size_t)krow*64 + ko);
        bf16x8 Bl1 = *(const bf16x8*)(Bl_p + (size_t)krow*64 + 32 + ko);
        f32x4 s = {0,0,0,0};
        s = __builtin_amdgcn_mfma_f32_16x16x32_bf16(Ah0, Bh0, s, 0, 0, 0);
        s = __builtin_amdgcn_mfma_f32_16x16x32_bf16(Ah1, Bh1, s, 0, 0, 0);
        s = __builtin_amdgcn_mfma_f32_16x16x32_bf16(Ah0, Bl0, s, 0, 0, 0);
        s = __builtin_amdgcn_mfma_f32_16x16x32_bf16(Ah1, Bl1, s, 0, 0, 0);
        s = __builtin_amdgcn_mfma_f32_16x16x32_bf16(Al0, Bh0, s, 0, 0, 0);
        s = __builtin_amdgcn_mfma_f32_16x16x32_bf16(Al1, Bh1, s, 0, 0, 0);
        const int kg = kc + wv*16 + l15;
        #pragma unroll
        for (int i = 0; i < 4; ++i) {
            const int q = q0 + g*4 + i;
            float e = (kg <= q) ? fast_exp2(__builtin_fmaf(s[i], pscale, pshift)) : 0.f;
            lacc[i] += e;
            Pl[(g*4+i)*72 + wv*16 + l15] = f2bf(e);
        }
        __syncthreads();
        #pragma unroll
        for (int ks = 0; ks < 2; ++ks) {
            bf16x8 af = *(const bf16x8*)(Pl + l15*72 + ks*32 + g*8);
            bf16x8 bf_ = *(const bf16x8*)(Vb + (size_t)(wv*16 + l15)*1024 + kc + ks*32 + g*8);
            oacc = __builtin_amdgcn_mfma_f32_16x16x32_bf16(af, bf_, oacc, 0, 0, 0);
        }
        __syncthreads();
    }
    #pragma unroll
    for (int off = 8; off >= 1; off >>= 1) {
        lacc[0] += __shfl_xor(lacc[0], off, 64);
        lacc[1] += __shfl_xor(lacc[1], off, 64);
        lacc[2] += __shfl_xor(lacc[2], off, 64);
        lacc[3] += __shfl_xor(lacc[3], off, 64);
    }
    if (l15 == 0) {
        #pragma unroll
        for (int i = 0; i < 4; ++i) lpart[wv][g*4 + i] = lacc[i];
    }
    __syncthreads();
    const size_t slot = (size_t)(br*2 + split);
    if (t < 16) {
        float l = lpart[0][t] + lpart[1][t] + lpart[2][t] + lpart[3][t];
        lb[slot*((size_t)BB*SS) + (size_t)b*SS + q0 + t] = l;
    }
    float* pob = po + slot*((size_t)NSD) + ((size_t)b*SS + q0)*64;
    #pragma unroll
    for (int i = 0; i < 4; ++i)
        pob[(size_t)(g*4 + i)*64 + wv*16 + l15] = oacc[i];
}

// ---------------------------------------------------------------------------
// K3: out = w0*(p0+p1)/(l0+l1) + w1*(p2+p3)/(l2+l3) + w2*(br3 slots s < ns)
// ns per row = min(8, qt/4+1), qt = 16-row tile index.
// ---------------------------------------------------------------------------
__global__ __launch_bounds__(256) void k_comb(
    const float* __restrict__ po, const float* __restrict__ lb,
    const float* __restrict__ attn_w, float* __restrict__ out)
{
    const int v = blockIdx.x*256 + threadIdx.x;      // f32x4 index over [B,S,D]
    const int qg = v >> 4;                           // global row b*S+q
    const int qt = (qg & 1023) >> 4;
    int ns = (qt >> 2) + 1; if (ns > 8) ns = 8;
    const float aw0 = attn_w[0], aw1 = attn_w[1], aw2 = attn_w[2];
    const float iws = fast_rcp(aw0 + aw1 + aw2);
    const f32x4* p = (const f32x4*)po;
    const int NQ = BB*SS;

    f32x4 s01 = p[(size_t)0*65536 + v] + p[(size_t)1*65536 + v];
    f32x4 s23 = p[(size_t)2*65536 + v] + p[(size_t)3*65536 + v];
    f32x4 s3s = {0,0,0,0};
    float l3 = 0.f;
    #pragma unroll
    for (int s = 0; s < 8; ++s) {
        if (s < ns) {
            s3s += p[(size_t)(4+s)*65536 + v];
            l3 += lb[(4+s)*NQ + qg];
        }
    }
    const float f0 = aw0 * iws * fast_rcp(lb[0*NQ + qg] + lb[1*NQ + qg]);
    const float f1 = aw1 * iws * fast_rcp(lb[2*NQ + qg] + lb[3*NQ + qg]);
    const float f2 = aw2 * iws * fast_rcp(l3);
    f32x4 o;
    #pragma unroll
    for (int u = 0; u < 4; ++u)
        o[u] = __builtin_fmaf(s01[u], f0,
               __builtin_fmaf(s23[u], f1, s3s[u]*f2));
    ((f32x4*)out)[v] = o;
}

extern "C" void kernel_launch(void* const* d_in, const int* in_sizes, int n_in,
                              void* d_out, int out_size, void* d_ws, size_t ws_size,
                              hipStream_t stream) {
    (void)in_sizes; (void)n_in; (void)out_size; (void)ws_size;
    const float* x          = (const float*)d_in[0];
    const float* Wq         = (const float*)d_in[1];
    const float* Wk         = (const float*)d_in[2];
    const float* bk         = (const float*)d_in[3];
    const float* Wv         = (const float*)d_in[4];
    const float* attn_w     = (const float*)d_in[5];
    const float* attn_scale = (const float*)d_in[6];
    float* out              = (float*)d_out;

    // workspace carve-up (~21.5 MB)
    float* exf   = (float*)d_ws;                          // [B,S,64] f32
    float* exfT4 = exf + NSD;                             // [B,16,S,4] f32
    unsigned short* qh  = (unsigned short*)(exfT4 + NSD); // 6 bf16 [B,S,64]
    unsigned short* ql  = qh  + NSD;
    unsigned short* kh  = ql  + NSD;
    unsigned short* kl  = kh  + NSD;
    unsigned short* xh  = kl  + NSD;
    unsigned short* xlo = xh  + NSD;
    unsigned short* xT  = xlo + NSD;                      // bf16 [B,64,S]
    unsigned short* vT  = xT  + NSD;
    float* po = (float*)(vT + NSD);                       // [12][B,S,64] f32
    float* lb = po + (size_t)12*NSD;                      // [12][B*S]

    k_proj <<<1024, 256, 0, stream>>>(x, Wq, Wk, bk, Wv,
                                      qh, ql, kh, kl, xh, xlo, exf, exfT4, xT, vT);
    k_br3  <<<512, 256, 0, stream>>>(exf, exfT4, xT, po, lb);
    k_br12 <<<1024, 256, 0, stream>>>(xh, xlo, qh, ql, kh, kl, xT, vT,
                                      attn_scale, po, lb);
    k_comb <<<256, 256, 0, stream>>>(po, lb, attn_w, out);
}